// Round 1
// 790.335 us; speedup vs baseline: 1.0528x; 1.0528x over previous
//
#include <hip/hip_runtime.h>
#include <hip/hip_bf16.h>
#include <math.h>

#define DIM 896
#define DD  (DIM * DIM)
#define NH 8
#define HD 112
#define BB 64
#define TT 8
#define KA 65
#define KAPAD 4224   // 64*65 = 4160 padded to 33*128
#define KT 512
#define NKEYS (TT + KA + KT)   // 585
#define CH 4096                // h_t conversion chunk rows (8 chunks)

#define EPI_NONE  0
#define EPI_ROPE  1
#define EPI_RESID 2
#define EPI_RELU  3

// -log2(10000)/56
#define NEG_L2_10K_OVER_56 (-0.2373327285062406f)

#ifndef __has_builtin
#define __has_builtin(x) 0
#endif
#if __has_builtin(__builtin_amdgcn_global_load_lds)
#define HAS_GLL 1
#else
#define HAS_GLL 0
#endif

typedef __attribute__((ext_vector_type(8))) short bf16x8_t;   // 8 bf16 (4 VGPRs)
typedef __attribute__((ext_vector_type(4))) float f32x4_t;    // MFMA accumulator

__device__ __forceinline__ short f2bf(float f) {
  unsigned u = __float_as_uint(f);
  u += 0x7fffu + ((u >> 16) & 1u);
  return (short)(u >> 16);
}
__device__ __forceinline__ float bf2f(short s) {
  return __uint_as_float(((unsigned)(unsigned short)s) << 16);
}

// ---------------- 9-way weight transpose: W[k][n] f32 -> Wt[n][k] bf16 ----------------
struct W9 { const float* w[9]; };

__global__ __launch_bounds__(256) void wtrans(W9 ws, short* __restrict__ Wt)
{
  __shared__ float t[32][33];
  const float* W = ws.w[blockIdx.z];
  short* dst = Wt + (size_t)blockIdx.z * DD;
  const int bx = blockIdx.x, by = blockIdx.y;
  const int tx = threadIdx.x & 31, ty = threadIdx.x >> 5;
#pragma unroll
  for (int i = 0; i < 4; ++i)
    t[ty + i * 8][tx] = W[(size_t)(by * 32 + ty + i * 8) * DIM + bx * 32 + tx];
  __syncthreads();
#pragma unroll
  for (int i = 0; i < 4; ++i)
    dst[(size_t)(bx * 32 + ty + i * 8) * DIM + by * 32 + tx] = f2bf(t[tx][ty + i * 8]);
}

// ---------------- fp32 -> bf16 elementwise (n8 = n/8 vector groups) ----------------
__global__ __launch_bounds__(256) void convert_bf16(
    const float* __restrict__ src, short* __restrict__ dst, int n8)
{
  const int i = blockIdx.x * 256 + threadIdx.x;
  if (i >= n8) return;
  const float4 a = ((const float4*)src)[i * 2];
  const float4 b = ((const float4*)src)[i * 2 + 1];
  bf16x8_t o;
  o[0] = f2bf(a.x); o[1] = f2bf(a.y); o[2] = f2bf(a.z); o[3] = f2bf(a.w);
  o[4] = f2bf(b.x); o[5] = f2bf(b.y); o[6] = f2bf(b.z); o[7] = f2bf(b.w);
  ((bf16x8_t*)dst)[i] = o;
}

// ---------------- h_ad = concat(h_a, p) -> bf16, zero-padded to 4224 rows ----------------
__global__ __launch_bounds__(256) void build_had(
    const float* __restrict__ h_a, const float* __restrict__ p,
    short* __restrict__ had)
{
  const int i = blockIdx.x * 256 + threadIdx.x;  // one per 8 elements
  const int total = KAPAD * DIM / 8;
  if (i >= total) return;
  const int c = (i % 112) * 8;
  const int row = i / 112;
  bf16x8_t o;
  if (row >= BB * KA) {
#pragma unroll
    for (int j = 0; j < 8; ++j) o[j] = 0;
  } else {
    const int b = row / KA, j = row % KA;
    const float* src = (j < KA - 1) ? h_a + ((size_t)b * (KA - 1) + j) * DIM + c
                                    : p + (size_t)b * DIM + c;
    const float4 a = *(const float4*)src;
    const float4 d = *(const float4*)(src + 4);
    o[0] = f2bf(a.x); o[1] = f2bf(a.y); o[2] = f2bf(a.z); o[3] = f2bf(a.w);
    o[4] = f2bf(d.x); o[5] = f2bf(d.y); o[6] = f2bf(d.z); o[7] = f2bf(d.w);
  }
  ((bf16x8_t*)had)[i] = o;
}

// ---------------- MFMA GEMM (m97 structure: gll both operands) ----------------
// C[M x N] = A[M x 896](bf16) @ Wt[N x 896](bf16, n-major) + bias, N = nsubs*896.
// 128x128 tile, BK=32, 4 waves x (4x4 of 16x16x32). Each block's 128 cols lie in
// exactly one 896-col sub-matrix (sub = blockIdx.x / 7), each with its own epilogue.
// hm[sub] != 0 => head-major bf16 store: out[((b*NH+h)*hm_ltot + l)*HD + d],
// with grow = b*hm_L + l, col = h*HD + d; rows with b >= BB are dropped (A-pad).
struct EpiCfg {
  const float* bias[3];
  float* outF[3];
  short* outB[3];
  const float* resid;
  int epi[3];
  int pos_mod[3];
  int row_off;     // global row offset (h_t chunking)
  int hm[3];       // head-major store flag
  int hm_L[3];     // rows per batch (grow decode)
  int hm_ltot[3];  // row stride per (b,h) in the destination
};

__global__ __launch_bounds__(256) void gemm_bf16(
    const short* __restrict__ A, const short* __restrict__ Wt, EpiCfg cfg)
{
  __shared__ __align__(16) short As[128 * 32];  // [m][k] 64 B rows
  __shared__ __align__(16) short Bs[128 * 32];  // [n][k]
  const int tid = threadIdx.x;
  const int wave = tid >> 6, lane = tid & 63;
  const int sub = blockIdx.x / 7;
  const int col0 = (blockIdx.x % 7) * 128;      // within sub
  const int row0 = blockIdx.y * 128;
  const int wm = wave >> 1, wn = wave & 1;
  const int lm = lane & 15, lq = lane >> 4;

  // staging source: lane -> row-in-16 = lane>>2, k-octet = (lane&3)*8
  const int sm = lane >> 2, sk = (lane & 3) * 8;
  const short* Ag0 = A + (size_t)(row0 + wave * 32 + sm) * DIM + sk;
  const short* Ag1 = Ag0 + (size_t)16 * DIM;
  const short* Wg0 = Wt + (size_t)(sub * DIM + col0 + wave * 32 + sm) * DIM + sk;
  const short* Wg1 = Wg0 + (size_t)16 * DIM;

  f32x4_t acc[4][4];
#pragma unroll
  for (int i = 0; i < 4; ++i)
#pragma unroll
    for (int j = 0; j < 4; ++j) acc[i][j] = (f32x4_t){0.f, 0.f, 0.f, 0.f};

  for (int k0 = 0; k0 < DIM; k0 += 32) {
    __syncthreads();
#if HAS_GLL
    __builtin_amdgcn_global_load_lds(
        (const __attribute__((address_space(1))) unsigned*)(Ag0 + k0),
        (__attribute__((address_space(3))) unsigned*)&As[(wave * 32) * 32], 16, 0, 0);
    __builtin_amdgcn_global_load_lds(
        (const __attribute__((address_space(1))) unsigned*)(Ag1 + k0),
        (__attribute__((address_space(3))) unsigned*)&As[(wave * 32 + 16) * 32], 16, 0, 0);
    __builtin_amdgcn_global_load_lds(
        (const __attribute__((address_space(1))) unsigned*)(Wg0 + k0),
        (__attribute__((address_space(3))) unsigned*)&Bs[(wave * 32) * 32], 16, 0, 0);
    __builtin_amdgcn_global_load_lds(
        (const __attribute__((address_space(1))) unsigned*)(Wg1 + k0),
        (__attribute__((address_space(3))) unsigned*)&Bs[(wave * 32 + 16) * 32], 16, 0, 0);
#else
    {
      const int m = tid >> 1, kh = (tid & 1) * 16;
      *(bf16x8_t*)&As[m * 32 + kh] =
          *(const bf16x8_t*)(A + (size_t)(row0 + m) * DIM + k0 + kh);
      *(bf16x8_t*)&As[m * 32 + kh + 8] =
          *(const bf16x8_t*)(A + (size_t)(row0 + m) * DIM + k0 + kh + 8);
      *(bf16x8_t*)&Bs[m * 32 + kh] =
          *(const bf16x8_t*)(Wt + (size_t)(sub * DIM + col0 + m) * DIM + k0 + kh);
      *(bf16x8_t*)&Bs[m * 32 + kh + 8] =
          *(const bf16x8_t*)(Wt + (size_t)(sub * DIM + col0 + m) * DIM + k0 + kh + 8);
    }
#endif
    __syncthreads();

    bf16x8_t af[4], bfr[4];
#pragma unroll
    for (int t = 0; t < 4; ++t)
      af[t] = *(const bf16x8_t*)&As[(wm * 64 + t * 16 + lm) * 32 + lq * 8];
#pragma unroll
    for (int t = 0; t < 4; ++t)
      bfr[t] = *(const bf16x8_t*)&Bs[(wn * 64 + t * 16 + lm) * 32 + lq * 8];
#pragma unroll
    for (int tm = 0; tm < 4; ++tm)
#pragma unroll
      for (int tn = 0; tn < 4; ++tn)
        acc[tm][tn] = __builtin_amdgcn_mfma_f32_16x16x32_bf16(
            af[tm], bfr[tn], acc[tm][tn], 0, 0, 0);
  }

  // epilogue — C/D frag: row = lq*4 + reg, col = lm (per 16x16 tile)
  const float* bias = cfg.bias[sub];
  float* outF = cfg.outF[sub];
  short* outB = cfg.outB[sub];
  const int epi = cfg.epi[sub], pm = cfg.pos_mod[sub];
  const int hm = cfg.hm[sub];
  const int L = cfg.hm_L[sub], ltot = cfg.hm_ltot[sub];
  int gb[4][4], gl[4][4];
  if (hm) {
#pragma unroll
    for (int tm = 0; tm < 4; ++tm) {
      const int g = cfg.row_off + row0 + wm * 64 + tm * 16 + lq * 4;
      int bq2 = g / L;
      int l = g - bq2 * L;
#pragma unroll
      for (int r = 0; r < 4; ++r) {
        gb[tm][r] = bq2; gl[tm][r] = l;
        if (++l == L) { l = 0; ++bq2; }
      }
    }
  }
#pragma unroll
  for (int tn = 0; tn < 4; ++tn) {
    const int col = col0 + wn * 64 + tn * 16 + lm;
    const float bv = bias[col];
    int hcol = 0, dcol = 0;
    if (hm) { hcol = col / HD; dcol = col - hcol * HD; }
    float fr = 0.f, sgn = 0.f;
    if (epi == EPI_ROPE) {
      const int d0 = col % HD;
      fr = exp2f((float)(d0 % 56) * NEG_L2_10K_OVER_56);
      sgn = (d0 & 1) ? 1.f : -1.f;
    }
#pragma unroll
    for (int tm = 0; tm < 4; ++tm) {
#pragma unroll
      for (int r = 0; r < 4; ++r) {
        const int grow = cfg.row_off + row0 + wm * 64 + tm * 16 + lq * 4 + r;
        float v = acc[tm][tn][r] + bv;
        if (epi == EPI_ROPE) {
          const float prt = __shfl_xor(v, 1);  // partner col (lane^1), pre-rope
          const int pos = hm ? gl[tm][r] : (grow % pm);
          float s, c;
          __sincosf((float)pos * fr, &s, &c);
          v = v * c + sgn * prt * s;
        } else if (epi == EPI_RESID) {
          v += cfg.resid[(size_t)grow * DIM + col];
        } else if (epi == EPI_RELU) {
          v = fmaxf(v, 0.f);
        }
        if (hm) {
          if (gb[tm][r] < BB)
            outB[((size_t)(gb[tm][r] * NH + hcol) * ltot + gl[tm][r]) * HD + dcol] =
                f2bf(v);
        } else if (outB) {
          outB[(size_t)grow * DIM + col] = f2bf(v);
        } else {
          outF[(size_t)grow * DIM + col] = v;
        }
      }
    }
  }
}

// ---------------- attention: one 1024-thread block per (b,h) ----------------
// Inputs are head-major: q [b][h][8][112]; kall/vall [b][h][585][112] with key
// segments s(0..7) | a(8..72) | t(73..584). Output row-major [b*8+t][DIM].
#define SCP 10   // score row stride (floats): conflict-free (gcd(10,32)=2), float2-aligned

__global__ __launch_bounds__(1024, 8) void attn_kernel(
    const short* __restrict__ q, const short* __restrict__ kall,
    const short* __restrict__ vall, const float* __restrict__ gate,
    short* __restrict__ out)
{
  __shared__ __align__(16) float qs[TT * HD];        // 3584 B
  __shared__ __align__(16) float sc[NKEYS * SCP];    // 23400 B, [k][t] padded
  __shared__ float red[TT * TT * HD];                // 28672 B, [g][t][d]
  __shared__ float isum[TT];
  const int tid = threadIdx.x;
  const int bh = blockIdx.x;
  const float scale = 0.09449111825230681f;  // 1/sqrt(112)
  const float rg = tanhf(gate[0]);

  // phase 0: q -> fp32 LDS (contiguous head-major load)
  if (tid < TT * HD) qs[tid] = bf2f(q[(size_t)bh * (TT * HD) + tid]);
  __syncthreads();

  // phase 1: scores — one thread per key, contiguous 224 B key row
  if (tid < NKEYS) {
    const int k = tid;
    const short* kp = kall + ((size_t)bh * NKEYS + k) * HD;
    float dot[TT] = {};
    for (int d8 = 0; d8 < HD; d8 += 8) {
      const bf16x8_t kv8 = *(const bf16x8_t*)(kp + d8);
      float kf[8];
#pragma unroll
      for (int j = 0; j < 8; ++j) kf[j] = bf2f(kv8[j]);
#pragma unroll
      for (int t = 0; t < TT; ++t) {
        const float4 qa = *(const float4*)&qs[t * HD + d8];
        const float4 qb4 = *(const float4*)&qs[t * HD + d8 + 4];
        dot[t] = fmaf(qa.x, kf[0], dot[t]);
        dot[t] = fmaf(qa.y, kf[1], dot[t]);
        dot[t] = fmaf(qa.z, kf[2], dot[t]);
        dot[t] = fmaf(qa.w, kf[3], dot[t]);
        dot[t] = fmaf(qb4.x, kf[4], dot[t]);
        dot[t] = fmaf(qb4.y, kf[5], dot[t]);
        dot[t] = fmaf(qb4.z, kf[6], dot[t]);
        dot[t] = fmaf(qb4.w, kf[7], dot[t]);
      }
    }
    const float s = (k >= TT + KA) ? scale * rg : scale;
#pragma unroll
    for (int t = 0; t < TT; ++t) sc[k * SCP + t] = dot[t] * s;
  }
  __syncthreads();

  // phase 2: softmax per t-row, one wave per row
  const int wave = tid >> 6, lane = tid & 63;
  if (wave < TT) {
    const int t = wave;
    float m = -1e30f;
    for (int k = lane; k < NKEYS; k += 64) m = fmaxf(m, sc[k * SCP + t]);
#pragma unroll
    for (int o = 32; o >= 1; o >>= 1) m = fmaxf(m, __shfl_xor(m, o));
    float sum = 0.f;
    for (int k = lane; k < NKEYS; k += 64) {
      const float e = expf(sc[k * SCP + t] - m);
      sc[k * SCP + t] = e;
      sum += e;
    }
#pragma unroll
    for (int o = 32; o >= 1; o >>= 1) sum += __shfl_xor(sum, o);
    if (lane == 0) isum[t] = 1.f / sum;
  }
  __syncthreads();

  // phase 3: PV partials — keys split 8 ways, each thread owns (group g, dim d),
  // accumulates all 8 t's; v read from HBM exactly once, coalesced over d.
  if (tid < TT * HD) {
    const int g = tid / HD, d = tid - g * HD;
    const int kb = (g * NKEYS) / TT, ke = ((g + 1) * NKEYS) / TT;
    const short* vp = vall + (size_t)bh * (NKEYS * HD) + d;
    float acc[TT] = {};
    for (int k = kb; k < ke; ++k) {
      const float vv = bf2f(vp[(size_t)k * HD]);
      const float2 s0 = *(const float2*)&sc[k * SCP];
      const float2 s1 = *(const float2*)&sc[k * SCP + 2];
      const float2 s2 = *(const float2*)&sc[k * SCP + 4];
      const float2 s3 = *(const float2*)&sc[k * SCP + 6];
      acc[0] = fmaf(s0.x, vv, acc[0]);
      acc[1] = fmaf(s0.y, vv, acc[1]);
      acc[2] = fmaf(s1.x, vv, acc[2]);
      acc[3] = fmaf(s1.y, vv, acc[3]);
      acc[4] = fmaf(s2.x, vv, acc[4]);
      acc[5] = fmaf(s2.y, vv, acc[5]);
      acc[6] = fmaf(s3.x, vv, acc[6]);
      acc[7] = fmaf(s3.y, vv, acc[7]);
    }
#pragma unroll
    for (int t = 0; t < TT; ++t) red[(g * TT + t) * HD + d] = acc[t];
  }
  __syncthreads();

  // phase 4: cross-group reduce + normalize + store (row-major for out-proj)
  if (tid < TT * HD) {
    const int t = tid / HD, d = tid - t * HD;
    float a = 0.f;
#pragma unroll
    for (int g = 0; g < TT; ++g) a += red[(g * TT + t) * HD + d];
    out[((size_t)(bh >> 3) * TT + t) * DIM + (bh & 7) * HD + d] = f2bf(a * isum[t]);
  }
}

// ---------------- layernorm: fp32 in -> bf16 out ----------------
__global__ __launch_bounds__(256) void ln_kernel(
    const float* __restrict__ y, const float* __restrict__ g,
    const float* __restrict__ beta, short* __restrict__ yn)
{
  __shared__ float s1[4], s2[4];
  const int r = blockIdx.x, tid = threadIdx.x;
  const float* row = y + (size_t)r * DIM;
  float sum = 0.f, sq = 0.f;
  for (int c = tid; c < DIM; c += 256) {
    const float v = row[c];
    sum += v;
    sq = fmaf(v, v, sq);
  }
#pragma unroll
  for (int o = 32; o >= 1; o >>= 1) {
    sum += __shfl_xor(sum, o);
    sq  += __shfl_xor(sq, o);
  }
  const int wave = tid >> 6, lane = tid & 63;
  if (lane == 0) { s1[wave] = sum; s2[wave] = sq; }
  __syncthreads();
  sum = s1[0] + s1[1] + s1[2] + s1[3];
  sq  = s2[0] + s2[1] + s2[2] + s2[3];
  const float mu = sum / DIM;
  const float var = sq / DIM - mu * mu;
  const float rstd = 1.f / sqrtf(var + 1e-5f);
  for (int c = tid; c < DIM; c += 256)
    yn[(size_t)r * DIM + c] = f2bf((row[c] - mu) * rstd * g[c] + beta[c]);
}

// ---------------- launch ----------------
extern "C" void kernel_launch(void* const* d_in, const int* in_sizes, int n_in,
                              void* d_out, int out_size, void* d_ws, size_t ws_size,
                              hipStream_t stream)
{
  const float* x   = (const float*)d_in[0];
  const float* h_a = (const float*)d_in[1];
  const float* h_t = (const float*)d_in[2];
  const float* p   = (const float*)d_in[3];
  const float* Wq  = (const float*)d_in[4];  const float* bq  = (const float*)d_in[5];
  const float* Wks = (const float*)d_in[6];  const float* bks = (const float*)d_in[7];
  const float* Wvs = (const float*)d_in[8];  const float* bvs = (const float*)d_in[9];
  const float* Wka = (const float*)d_in[10]; const float* bka = (const float*)d_in[11];
  const float* Wva = (const float*)d_in[12]; const float* bva = (const float*)d_in[13];
  const float* Wkt = (const float*)d_in[14]; const float* bkt = (const float*)d_in[15];
  const float* Wvt = (const float*)d_in[16]; const float* bvt = (const float*)d_in[17];
  const float* Wo  = (const float*)d_in[18]; const float* bo  = (const float*)d_in[19];
  const float* Wf  = (const float*)d_in[20]; const float* bf_ = (const float*)d_in[21];
  const float* gate = (const float*)d_in[22];
  const float* ln_g = (const float*)d_in[23];
  const float* ln_b = (const float*)d_in[24];

  // ---- workspace layout (bytes). Total = 161.71 MB < round-3-proven 167.67 MB ----
  const size_t SZ_HAD = (size_t)KAPAD * DIM * 2;            // bf16
  const size_t SZ_SM  = (size_t)BB * TT * DIM * 2;          // bf16 small [512 x 896]
  const size_t SZ_KV  = (size_t)BB * NH * NKEYS * HD * 2;   // bf16 [b][h][585][112]
  const size_t SZ_WT  = (size_t)9 * DD * 2;                 // 9 weights bf16
  const size_t needed = SZ_HAD + SZ_SM * 4 + SZ_KV * 2 + SZ_WT
                        + (size_t)BB * TT * DIM * 4;        // + yb fp32
  if (ws_size < needed) return;  // fail loud, not UB

  char* wsp = (char*)d_ws;
  short* hadb = (short*)wsp; wsp += SZ_HAD;
  short* xb   = (short*)wsp; wsp += SZ_SM;
  short* qb   = (short*)wsp; wsp += SZ_SM;   // head-major [b][h][8][112]
  short* kall = (short*)wsp; wsp += SZ_KV;   // head-major [b][h][585][112]
  short* vall = (short*)wsp; wsp += SZ_KV;
  short* WtA  = (short*)wsp; wsp += SZ_WT;
  short* attn_outb = (short*)wsp; wsp += SZ_SM;
  float* yb   = (float*)wsp; wsp += (size_t)BB * TT * DIM * 4;
  short* ynb  = (short*)wsp; wsp += SZ_SM;
  // h_t conversion scratch aliases weights 0..4 (Wq..Wva), dead once GEMM-S/A ran.
  // CH*DIM*2 = 7,340,032 B < 5*DD*2 = 8,028,160 B; live WtKt starts at 5*DD. ✓
  short* scratch = WtA;

  dim3 blk(256);

  // 0) transpose all 9 weights -> bf16 [n][k], concatenated
  W9 w9; const float* Ws[9] = {Wq, Wks, Wvs, Wka, Wva, Wkt, Wvt, Wo, Wf};
  for (int i = 0; i < 9; ++i) w9.w[i] = Ws[i];
  wtrans<<<dim3(28, 28, 9), blk, 0, stream>>>(w9, WtA);

  // 1) activations -> bf16
  convert_bf16<<<(BB * TT * DIM / 8 + 255) / 256, blk, 0, stream>>>(x, xb, BB * TT * DIM / 8);
  build_had<<<(KAPAD * DIM / 8 + 255) / 256, blk, 0, stream>>>(h_a, p, hadb);

  // 2) fused S-group GEMM: [q | k_s | v_s] = xb @ [Wq|Wks|Wvs] (head-major out)
  {
    EpiCfg c = {};
    c.bias[0] = bq;  c.outB[0] = qb;   c.epi[0] = EPI_ROPE; c.pos_mod[0] = TT;
    c.hm[0] = 1; c.hm_L[0] = TT; c.hm_ltot[0] = TT;
    c.bias[1] = bks; c.outB[1] = kall; c.epi[1] = EPI_ROPE; c.pos_mod[1] = TT;
    c.hm[1] = 1; c.hm_L[1] = TT; c.hm_ltot[1] = NKEYS;
    c.bias[2] = bvs; c.outB[2] = vall; c.epi[2] = EPI_NONE; c.pos_mod[2] = 1;
    c.hm[2] = 1; c.hm_L[2] = TT; c.hm_ltot[2] = NKEYS;
    gemm_bf16<<<dim3(21, BB * TT / 128), blk, 0, stream>>>(xb, WtA, c);
  }
  // 3) fused A-group GEMM: [k_a | v_a] = hadb @ [Wka|Wva] (head-major, seg off 8)
  {
    EpiCfg c = {};
    c.bias[0] = bka; c.outB[0] = kall + (size_t)TT * HD; c.epi[0] = EPI_ROPE;
    c.pos_mod[0] = KA; c.hm[0] = 1; c.hm_L[0] = KA; c.hm_ltot[0] = NKEYS;
    c.bias[1] = bva; c.outB[1] = vall + (size_t)TT * HD; c.epi[1] = EPI_NONE;
    c.pos_mod[1] = 1; c.hm[1] = 1; c.hm_L[1] = KA; c.hm_ltot[1] = NKEYS;
    gemm_bf16<<<dim3(14, KAPAD / 128), blk, 0, stream>>>(hadb, WtA + (size_t)3 * DD, c);
  }
  // 4) chunked T-group GEMM: [k_t | v_t] = h_t @ [Wkt|Wvt] (head-major, seg off 73)
  for (int m0 = 0; m0 < BB * KT; m0 += CH) {
    convert_bf16<<<(CH * DIM / 8 + 255) / 256, blk, 0, stream>>>(
        h_t + (size_t)m0 * DIM, scratch, CH * DIM / 8);
    EpiCfg c = {};
    c.bias[0] = bkt; c.outB[0] = kall + (size_t)(TT + KA) * HD; c.epi[0] = EPI_ROPE;
    c.pos_mod[0] = KT; c.hm[0] = 1; c.hm_L[0] = KT; c.hm_ltot[0] = NKEYS;
    c.bias[1] = bvt; c.outB[1] = vall + (size_t)(TT + KA) * HD; c.epi[1] = EPI_NONE;
    c.pos_mod[1] = 1; c.hm[1] = 1; c.hm_L[1] = KT; c.hm_ltot[1] = NKEYS;
    c.row_off = m0;
    gemm_bf16<<<dim3(14, CH / 128), blk, 0, stream>>>(scratch, WtA + (size_t)5 * DD, c);
  }

  // 5) attention — 1024 threads/block, 2 blocks/CU => 32 waves/CU
  attn_kernel<<<BB * NH, dim3(1024), 0, stream>>>(qb, kall, vall, gate, attn_outb);

  // 6) out-proj + residual (fp32 out), LN (bf16 out), FFN + ReLU (fp32 d_out)
  {
    EpiCfg c = {};
    c.bias[0] = bo; c.outF[0] = yb; c.epi[0] = EPI_RESID; c.pos_mod[0] = 1;
    c.resid = x;
    gemm_bf16<<<dim3(7, BB * TT / 128), blk, 0, stream>>>(attn_outb, WtA + (size_t)7 * DD, c);
  }
  ln_kernel<<<BB * TT, blk, 0, stream>>>(yb, ln_g, ln_b, ynb);
  {
    EpiCfg c = {};
    c.bias[0] = bf_; c.outF[0] = (float*)d_out; c.epi[0] = EPI_RELU; c.pos_mod[0] = 1;
    gemm_bf16<<<dim3(7, BB * TT / 128), blk, 0, stream>>>(ynb, WtA + (size_t)8 * DD, c);
  }
}